// Round 5
// baseline (2740.845 us; speedup 1.0000x reference)
//
#include <hip/hip_runtime.h>
#include <cstdint>

// Problem constants (fixed by the reference)
#define N_TRAIN 65536
#define N_TEST  4096
#define DIM     512
#define K_NN    5
#define NSEG    16
#define SEG     (N_TRAIN / NSEG)   // 4096 train cols per segment

// MFMA path tile config
#define GTM 128      // test rows per block
#define GTN 128      // train cols per tile
#define GBK 32       // K per step (one 16x16x32 MFMA)
#define NCAND (NSEG * K_NN)                 // 80 candidates per test row
#define NRES  24                            // exactly-rescored candidates
#define NSTEP ((SEG / GTN) * (DIM / GBK))   // 32 col-tiles * 16 k-steps = 512

typedef __bf16 bf16x8 __attribute__((ext_vector_type(8)));
typedef float  f32x4  __attribute__((ext_vector_type(4)));

#define GLDS16(g, l)                                                          \
    __builtin_amdgcn_global_load_lds(                                         \
        (__attribute__((address_space(1))) void*)(g),                         \
        (__attribute__((address_space(3))) void*)(l), 16, 0, 0)

// ---------------------------------------------------------------------------
// fp32 -> bf16 (RNE) helper
// ---------------------------------------------------------------------------
__device__ inline unsigned f2bf(float x) {
    unsigned u = __float_as_uint(x);
    return (u + 0x7FFFu + ((u >> 16) & 1u)) >> 16;
}

// ---------------------------------------------------------------------------
// Kernel 1: fused bf16 convert + squared L2 row norms. One wave per row.
// ---------------------------------------------------------------------------
__global__ __launch_bounds__(256) void cvtnorm_k(const float* __restrict__ in,
                                                 unsigned short* __restrict__ outb,
                                                 float* __restrict__ outn,
                                                 int nrows) {
    int row  = blockIdx.x * 4 + (threadIdx.x >> 6);
    int lane = threadIdx.x & 63;
    if (row >= nrows) return;
    const float4* p = (const float4*)(in + (size_t)row * DIM) + lane * 2;
    float4 a = p[0], b = p[1];
    float s = a.x*a.x + a.y*a.y + a.z*a.z + a.w*a.w
            + b.x*b.x + b.y*b.y + b.z*b.z + b.w*b.w;
    uint4 v;
    v.x = f2bf(a.x) | (f2bf(a.y) << 16);
    v.y = f2bf(a.z) | (f2bf(a.w) << 16);
    v.z = f2bf(b.x) | (f2bf(b.y) << 16);
    v.w = f2bf(b.z) | (f2bf(b.w) << 16);
    *((uint4*)(outb + (size_t)row * DIM) + lane) = v;
#pragma unroll
    for (int off = 32; off > 0; off >>= 1) s += __shfl_xor(s, off, 64);
    if (lane == 0) outn[row] = s;
}

// plain norms (fallback path)
__global__ __launch_bounds__(256) void norms_k(const float* __restrict__ X,
                                               float* __restrict__ out,
                                               int nrows) {
    int row  = blockIdx.x * 4 + (threadIdx.x >> 6);
    int lane = threadIdx.x & 63;
    if (row >= nrows) return;
    const float4* xp = (const float4*)(X + (size_t)row * DIM);
    float4 a = xp[lane];
    float4 b = xp[lane + 64];
    float s = a.x*a.x + a.y*a.y + a.z*a.z + a.w*a.w
            + b.x*b.x + b.y*b.y + b.z*b.z + b.w*b.w;
#pragma unroll
    for (int off = 32; off > 0; off >>= 1) s += __shfl_down(s, off, 64);
    if (lane == 0) out[row] = s;
}

// ---------------------------------------------------------------------------
// top-5 insertion (sorted ascending), uint64 keys
// ---------------------------------------------------------------------------
__device__ inline void ins5(unsigned long long key, unsigned long long* top) {
    if (key < top[4]) {
        unsigned long long k0 = top[0], k1 = top[1], k2 = top[2], k3 = top[3];
        top[0] = key < k0 ? key : k0;
        top[1] = key < k0 ? k0 : (key < k1 ? key : k1);
        top[2] = key < k1 ? k1 : (key < k2 ? key : k2);
        top[3] = key < k2 ? k2 : (key < k3 ? key : k3);
        top[4] = key < k3 ? k3 : key;
    }
}

// order-preserving float -> uint map (handles negatives)
__device__ inline unsigned fmono(float v) {
    unsigned u = __float_as_uint(v);
    return (u & 0x80000000u) ? ~u : (u | 0x80000000u);
}

// inverse: float threshold from the 5th-best key's high word
__device__ inline float thr_of(unsigned long long t4) {
    if (t4 == ~0ull) return __builtin_inff();
    unsigned u = (unsigned)(t4 >> 32);
    u = (u & 0x80000000u) ? (u ^ 0x80000000u) : ~u;
    return __uint_as_float(u);
}

// ---------------------------------------------------------------------------
// Kernel 2: bf16 MFMA distance GEMM + per-(row,seg) approx top-5.
// Block 256 thr (4 waves, 2x2 of 64x64). Tile 128x128, BK=32, double-buffered
// LDS with one-step global_load_lds prefetch. Epilogue: 4 passes of 32 cols
// through an 18 KB Ds buffer (total LDS 50 KB -> 3 blocks/CU), with a float
// min-tree prefilter before the u64 ins5 machinery.
// v = x2[col] - 2*cross (t2 is row-constant -> irrelevant for ordering).
// ---------------------------------------------------------------------------
__global__ __launch_bounds__(256, 3) void knn_mfma_k(
    const unsigned short* __restrict__ Xtrb,  // bf16 bits [N_TRAIN][DIM]
    const unsigned short* __restrict__ Xteb,  // bf16 bits [N_TEST][DIM]
    const float* __restrict__ x2,
    unsigned long long* __restrict__ cand)    // [N_TEST][NCAND]
{
    __shared__ __align__(16) unsigned short As[2][GTM * GBK];  // 2 x 8 KB
    __shared__ __align__(16) unsigned short Bs[2][GTN * GBK];  // 2 x 8 KB
    __shared__ __align__(16) float Ds[GTM * 36];               // 18 KB (32+4 pad)

    const int t     = threadIdx.x;
    const int lane  = t & 63;
    const int w     = t >> 6;
    const int wr    = w >> 1, wc = w & 1;
    const int col_l = lane & 15, quad = lane >> 4;
    const int row0  = blockIdx.x * GTM;
    const int seg0  = blockIdx.y * SEG;

    const int selrow = t >> 1;   // 0..127
    const int selh   = t & 1;    // 16-col half within a 32-col pass

    unsigned long long top[K_NN];
#pragma unroll
    for (int p = 0; p < K_NN; ++p) top[p] = ~0ull;
    float thr = __builtin_inff();

    // stage step s (col-tile s>>4, k-chunk s&15) into buffer b
    auto stage = [&](int s, int b) {
        const int k0   = (s & 15) * GBK;
        const int col0 = seg0 + (s >> 4) * GTN;
        const int s0 = t, s1 = 256 + t;
        GLDS16(Xteb + (size_t)(row0 + (s0 >> 2)) * DIM + k0 + (s0 & 3) * 8,
               &As[b][(w * 64) * 8]);
        GLDS16(Xteb + (size_t)(row0 + (s1 >> 2)) * DIM + k0 + (s1 & 3) * 8,
               &As[b][(256 + w * 64) * 8]);
        GLDS16(Xtrb + (size_t)(col0 + (s0 >> 2)) * DIM + k0 + (s0 & 3) * 8,
               &Bs[b][(w * 64) * 8]);
        GLDS16(Xtrb + (size_t)(col0 + (s1 >> 2)) * DIM + k0 + (s1 & 3) * 8,
               &Bs[b][(256 + w * 64) * 8]);
    };

    stage(0, 0);
    __syncthreads();   // compiler drains vmcnt(0) before the barrier

    for (int ct = 0; ct < SEG / GTN; ++ct) {
        const int col0 = seg0 + ct * GTN;
        f32x4 acc[4][4];
#pragma unroll
        for (int mt = 0; mt < 4; ++mt)
#pragma unroll
            for (int nt = 0; nt < 4; ++nt)
                acc[mt][nt] = (f32x4){0.f, 0.f, 0.f, 0.f};

#pragma unroll 2
        for (int kk = 0; kk < DIM / GBK; ++kk) {
            const int s = ct * (DIM / GBK) + kk;
            if (s + 1 < NSTEP) stage(s + 1, (s + 1) & 1);  // prefetch next step

            const unsigned short* Ab = As[s & 1];
            const unsigned short* Bb = Bs[s & 1];
            bf16x8 af[4], bfr[4];
#pragma unroll
            for (int mt = 0; mt < 4; ++mt)
                af[mt] = *(const bf16x8*)&Ab[(wr * 64 + mt * 16 + col_l) * GBK + quad * 8];
#pragma unroll
            for (int nt = 0; nt < 4; ++nt)
                bfr[nt] = *(const bf16x8*)&Bb[(wc * 64 + nt * 16 + col_l) * GBK + quad * 8];
#pragma unroll
            for (int mt = 0; mt < 4; ++mt)
#pragma unroll
                for (int nt = 0; nt < 4; ++nt)
                    acc[mt][nt] = __builtin_amdgcn_mfma_f32_16x16x32_bf16(
                        af[mt], bfr[nt], acc[mt][nt], 0, 0, 0);

            __syncthreads();   // drains prefetch (vmcnt) + frag reads (lgkm)
        }

        // epilogue: four 32-col passes through Ds
#pragma unroll 1
        for (int p = 0; p < 4; ++p) {
            if (wc == (p >> 1)) {
                const int n0 = (p & 1) * 2;
#pragma unroll
                for (int q = 0; q < 2; ++q) {
                    const int nt = n0 + q;
                    const int lc = q * 16 + col_l;              // 0..31 in pass
                    const float xv = x2[col0 + p * 32 + lc];
#pragma unroll
                    for (int mt = 0; mt < 4; ++mt) {
                        const int rb = wr * 64 + mt * 16 + quad * 4;
                        f32x4 a = acc[mt][nt];
                        Ds[(rb + 0) * 36 + lc] = fmaf(-2.f, a.x, xv);
                        Ds[(rb + 1) * 36 + lc] = fmaf(-2.f, a.y, xv);
                        Ds[(rb + 2) * 36 + lc] = fmaf(-2.f, a.z, xv);
                        Ds[(rb + 3) * 36 + lc] = fmaf(-2.f, a.w, xv);
                    }
                }
            }
            __syncthreads();
            // selection: 2 threads per row, 16 cols each, min-tree prefilter
            const int colbase = col0 + p * 32 + selh * 16;
            const int base = selrow * 36 + selh * 16;
#pragma unroll
            for (int j = 0; j < 4; ++j) {
                f32x4 v = *(const f32x4*)&Ds[base + j * 4];
                float m = fminf(fminf(v.x, v.y), fminf(v.z, v.w));
                if (m <= thr) {
                    const int cb = colbase + j * 4;
                    ins5(((unsigned long long)fmono(v.x) << 32) | (unsigned)(cb + 0), top);
                    ins5(((unsigned long long)fmono(v.y) << 32) | (unsigned)(cb + 1), top);
                    ins5(((unsigned long long)fmono(v.z) << 32) | (unsigned)(cb + 2), top);
                    ins5(((unsigned long long)fmono(v.w) << 32) | (unsigned)(cb + 3), top);
                    thr = thr_of(top[4]);
                }
            }
            __syncthreads();   // scan done before next pass overwrites Ds
        }
    }

    // merge the two half-selectors per row -> 5 keys per (row, segment)
    unsigned long long* MB2 = (unsigned long long*)Ds;   // 128 rows x 10 u64
#pragma unroll
    for (int p = 0; p < K_NN; ++p) MB2[selrow * 10 + selh * 5 + p] = top[p];
    __syncthreads();
    if (selh == 0) {
        unsigned long long m5[K_NN];
#pragma unroll
        for (int p = 0; p < K_NN; ++p) m5[p] = ~0ull;
#pragma unroll
        for (int i = 0; i < 10; ++i) ins5(MB2[selrow * 10 + i], m5);
        unsigned long long* cr =
            cand + (size_t)(row0 + selrow) * NCAND + blockIdx.y * K_NN;
#pragma unroll
        for (int p = 0; p < K_NN; ++p) cr[p] = m5[p];
    }
}

// ---------------------------------------------------------------------------
// Kernel 3: fused approx-merge (80 -> top-24) + exact fp32 rescore + vote.
// One wave per test row. Safety: true top-5 are approx-rank <= 24 with
// overwhelming margin (noise sigma ~0.1 vs order-stat gaps ~3 per rank).
// ---------------------------------------------------------------------------
__global__ __launch_bounds__(256) void rescore_vote_k(
    const float* __restrict__ Xtr, const float* __restrict__ Xte,
    const float* __restrict__ x2,  const float* __restrict__ t2,
    const unsigned long long* __restrict__ cand,
    const int* __restrict__ y, int* __restrict__ out)
{
    int row  = blockIdx.x * 4 + (threadIdx.x >> 6);
    int lane = threadIdx.x & 63;
    const unsigned long long* cr = cand + (size_t)row * NCAND;

    unsigned long long c0 = cr[lane];
    unsigned long long c1 = (lane < NCAND - 64) ? cr[64 + lane] : ~0ull;

    // iteratively extract the NRES smallest approx keys (all lanes get cols)
    unsigned cols[NRES];
#pragma unroll 1
    for (int i = 0; i < NRES; ++i) {
        unsigned long long m = c0 < c1 ? c0 : c1;
#pragma unroll
        for (int off = 32; off > 0; off >>= 1) {
            unsigned long long o = __shfl_xor(m, off, 64);
            m = o < m ? o : m;
        }
        cols[i] = (unsigned)(m & 0xffffffffu);
        if (c0 == m) c0 = ~0ull;
        if (c1 == m) c1 = ~0ull;
    }

    // exact fp32 rescore of the NRES candidates
    const float4* te = (const float4*)(Xte + (size_t)row * DIM);
    float4 e0 = te[lane * 2], e1 = te[lane * 2 + 1];
    float t2r = t2[row];
    float d2s[NRES];
#pragma unroll 4
    for (int i = 0; i < NRES; ++i) {
        const float4* tr = (const float4*)(Xtr + (size_t)cols[i] * DIM);
        float4 p = tr[lane * 2], q = tr[lane * 2 + 1];
        float s = e0.x * p.x;
        s = fmaf(e0.y, p.y, s); s = fmaf(e0.z, p.z, s); s = fmaf(e0.w, p.w, s);
        s = fmaf(e1.x, q.x, s); s = fmaf(e1.y, q.y, s);
        s = fmaf(e1.z, q.z, s); s = fmaf(e1.w, q.w, s);
#pragma unroll
        for (int off = 32; off > 0; off >>= 1) s += __shfl_xor(s, off, 64);
        d2s[i] = fmaxf(t2r + x2[cols[i]] - 2.0f * s, 0.0f);
    }

    // exact top-5 (all lanes redundantly) + mode vote on lane 0
    unsigned long long top[K_NN];
#pragma unroll
    for (int p = 0; p < K_NN; ++p) top[p] = ~0ull;
#pragma unroll
    for (int i = 0; i < NRES; ++i)
        ins5(((unsigned long long)__float_as_uint(d2s[i]) << 32) | cols[i], top);

    if (lane == 0) {
        int labs[K_NN];
#pragma unroll
        for (int p = 0; p < K_NN; ++p) labs[p] = y[(unsigned)(top[p] & 0xffffffffu)];
        int bestLab = 0x7fffffff, bestCnt = 0;
#pragma unroll
        for (int p = 0; p < K_NN; ++p) {
            int cnt = 0;
#pragma unroll
            for (int q = 0; q < K_NN; ++q) cnt += (labs[q] == labs[p]) ? 1 : 0;
            if (cnt > bestCnt || (cnt == bestCnt && labs[p] < bestLab)) {
                bestCnt = cnt; bestLab = labs[p];
            }
        }
        out[row] = bestLab;
    }
}

// ===========================================================================
// Fallback fp32 path (round-1, verified) in case ws_size is too small.
// ===========================================================================
#define FTM 64
#define FTN 128
#define FBK 16
#define FSEG (N_TRAIN / 8)

__global__ __launch_bounds__(256) void knn_tile_k(
    const float* __restrict__ Xtr, const float* __restrict__ Xte,
    const float* __restrict__ x2,  const float* __restrict__ t2,
    unsigned long long* __restrict__ cand)
{
    __shared__ float As[FBK][FTM];
    __shared__ float Bs[FBK][FTN];
    __shared__ unsigned long long MB[FTM][16 * K_NN];

    const int t   = threadIdx.x;
    const int ty  = t >> 4;
    const int tx  = t & 15;
    const int row0 = blockIdx.x * FTM;
    const int seg0 = blockIdx.y * FSEG;

    float t2r[4];
#pragma unroll
    for (int j = 0; j < 4; ++j) t2r[j] = t2[row0 + ty * 4 + j];

    unsigned long long top[4][K_NN];
#pragma unroll
    for (int j = 0; j < 4; ++j)
#pragma unroll
        for (int p = 0; p < K_NN; ++p) top[j][p] = ~0ull;

    const int srow = t >> 2;
    const int skq  = (t & 3) * 4;

    for (int ct = 0; ct < FSEG / FTN; ++ct) {
        const int col0 = seg0 + ct * FTN;
        float acc[4][8] = {};

        for (int k0 = 0; k0 < DIM; k0 += FBK) {
            float4 av  = *(const float4*)(Xte + (size_t)(row0 + srow) * DIM + k0 + skq);
            float4 bv0 = *(const float4*)(Xtr + (size_t)(col0 + srow) * DIM + k0 + skq);
            float4 bv1 = *(const float4*)(Xtr + (size_t)(col0 + 64 + srow) * DIM + k0 + skq);
            __syncthreads();
            As[skq + 0][srow] = av.x;  As[skq + 1][srow] = av.y;
            As[skq + 2][srow] = av.z;  As[skq + 3][srow] = av.w;
            Bs[skq + 0][srow] = bv0.x; Bs[skq + 1][srow] = bv0.y;
            Bs[skq + 2][srow] = bv0.z; Bs[skq + 3][srow] = bv0.w;
            Bs[skq + 0][srow + 64] = bv1.x; Bs[skq + 1][srow + 64] = bv1.y;
            Bs[skq + 2][srow + 64] = bv1.z; Bs[skq + 3][srow + 64] = bv1.w;
            __syncthreads();

#pragma unroll
            for (int k = 0; k < FBK; ++k) {
                float4 a  = *(const float4*)&As[k][ty * 4];
                float4 b0 = *(const float4*)&Bs[k][tx * 8];
                float4 b1 = *(const float4*)&Bs[k][tx * 8 + 4];
                float a4[4] = {a.x, a.y, a.z, a.w};
                float b8[8] = {b0.x, b0.y, b0.z, b0.w, b1.x, b1.y, b1.z, b1.w};
#pragma unroll
                for (int j = 0; j < 4; ++j)
#pragma unroll
                    for (int l = 0; l < 8; ++l)
                        acc[j][l] = fmaf(a4[j], b8[l], acc[j][l]);
            }
        }

#pragma unroll
        for (int j = 0; j < 4; ++j) {
#pragma unroll
            for (int l = 0; l < 8; ++l) {
                int col = col0 + tx * 8 + l;
                float d2 = fmaxf(t2r[j] + x2[col] - 2.0f * acc[j][l], 0.0f);
                unsigned long long key =
                    ((unsigned long long)__float_as_uint(d2) << 32) | (unsigned)col;
                ins5(key, top[j]);
            }
        }
    }

#pragma unroll
    for (int j = 0; j < 4; ++j)
#pragma unroll
        for (int p = 0; p < K_NN; ++p)
            MB[ty * 4 + j][tx * K_NN + p] = top[j][p];
    __syncthreads();

    if (t < FTM) {
        unsigned long long last = 0;
        for (int p = 0; p < K_NN; ++p) {
            unsigned long long best = ~0ull;
            for (int q = 0; q < 16 * K_NN; ++q) {
                unsigned long long v = MB[t][q];
                if (v > last && v < best) best = v;
            }
            cand[(size_t)(row0 + t) * 40 + blockIdx.y * K_NN + p] = best;
            last = best;
        }
    }
}

__global__ __launch_bounds__(256) void knn_final_k(
    const unsigned long long* __restrict__ cand,
    const int* __restrict__ y, int* __restrict__ out)
{
    int r = blockIdx.x * 256 + threadIdx.x;
    if (r >= N_TEST) return;
    const unsigned long long* c = cand + (size_t)r * 40;

    unsigned long long top[K_NN];
#pragma unroll
    for (int p = 0; p < K_NN; ++p) top[p] = ~0ull;
#pragma unroll
    for (int i = 0; i < 40; ++i) ins5(c[i], top);

    int labs[K_NN];
#pragma unroll
    for (int p = 0; p < K_NN; ++p) labs[p] = y[(unsigned)(top[p] & 0xffffffffu)];

    int bestLab = 0x7fffffff, bestCnt = 0;
#pragma unroll
    for (int p = 0; p < K_NN; ++p) {
        int cnt = 0;
#pragma unroll
        for (int q = 0; q < K_NN; ++q) cnt += (labs[q] == labs[p]) ? 1 : 0;
        if (cnt > bestCnt || (cnt == bestCnt && labs[p] < bestLab)) {
            bestCnt = cnt; bestLab = labs[p];
        }
    }
    out[r] = bestLab;
}

// ---------------------------------------------------------------------------
// Workspace layout (MFMA path), bytes:
//   [0,        262144)   x2     : 65536 f32
//   [262144,   278528)   t2     : 4096 f32
//   [278528,  2899968)   cand   : 4096 * 80 u64
//   [3145728, 7340032)   Xte_bf : 4096*512 bf16
//   [7340032, 74448896)  Xtr_bf : 65536*512 bf16
// ---------------------------------------------------------------------------
extern "C" void kernel_launch(void* const* d_in, const int* in_sizes, int n_in,
                              void* d_out, int out_size, void* d_ws, size_t ws_size,
                              hipStream_t stream) {
    const float* Xtr = (const float*)d_in[0];
    const float* Xte = (const float*)d_in[1];
    const int*   y   = (const int*)d_in[2];
    int* out = (int*)d_out;

    char* ws = (char*)d_ws;
    float* x2 = (float*)ws;
    float* t2 = (float*)(ws + 262144);
    unsigned long long* cand = (unsigned long long*)(ws + 278528);

    const size_t NEED = 74448896;

    if (ws_size >= NEED) {
        unsigned short* Xteb = (unsigned short*)(ws + 3145728);
        unsigned short* Xtrb = (unsigned short*)(ws + 7340032);

        cvtnorm_k<<<N_TRAIN / 4, 256, 0, stream>>>(Xtr, Xtrb, x2, N_TRAIN);
        cvtnorm_k<<<N_TEST / 4, 256, 0, stream>>>(Xte, Xteb, t2, N_TEST);

        knn_mfma_k<<<dim3(N_TEST / GTM, NSEG), 256, 0, stream>>>(Xtrb, Xteb, x2, cand);
        rescore_vote_k<<<N_TEST / 4, 256, 0, stream>>>(Xtr, Xte, x2, t2, cand, y, out);
    } else {
        // fp32 fallback (round-1 verified path); cand here is [N_TEST][40]
        norms_k<<<N_TRAIN / 4, 256, 0, stream>>>(Xtr, x2, N_TRAIN);
        norms_k<<<N_TEST / 4, 256, 0, stream>>>(Xte, t2, N_TEST);
        knn_tile_k<<<dim3(N_TEST / FTM, 8), 256, 0, stream>>>(Xtr, Xte, x2, t2, cand);
        knn_final_k<<<N_TEST / 256, 256, 0, stream>>>(cand, y, out);
    }
}

// Round 6
// 803.004 us; speedup vs baseline: 3.4132x; 3.4132x over previous
//
#include <hip/hip_runtime.h>
#include <cstdint>

// Problem constants (fixed by the reference)
#define N_TRAIN 65536
#define N_TEST  4096
#define DIM     512
#define K_NN    5
#define NSEG    16
#define SEG     (N_TRAIN / NSEG)   // 4096 train cols per segment

// MFMA path tile config
#define GTM 128      // test rows per block
#define GTN 128      // train cols per tile
#define GBK 32       // K per step (one 16x16x32 MFMA)
#define NCAND (NSEG * K_NN)                 // 80 candidates per test row
#define NRES  24                            // exactly-rescored candidates
#define NSTEP ((SEG / GTN) * (DIM / GBK))   // 32 col-tiles * 16 k-steps = 512

typedef __bf16 bf16x8 __attribute__((ext_vector_type(8)));
typedef float  f32x4  __attribute__((ext_vector_type(4)));

#define GLDS16(g, l)                                                          \
    __builtin_amdgcn_global_load_lds(                                         \
        (__attribute__((address_space(1))) void*)(g),                         \
        (__attribute__((address_space(3))) void*)(l), 16, 0, 0)

// ---------------------------------------------------------------------------
// fp32 -> bf16 (RNE) helper
// ---------------------------------------------------------------------------
__device__ inline unsigned f2bf(float x) {
    unsigned u = __float_as_uint(x);
    return (u + 0x7FFFu + ((u >> 16) & 1u)) >> 16;
}

// ---------------------------------------------------------------------------
// Kernel 1: fused bf16 convert + squared L2 row norms. One wave per row.
// ---------------------------------------------------------------------------
__global__ __launch_bounds__(256) void cvtnorm_k(const float* __restrict__ in,
                                                 unsigned short* __restrict__ outb,
                                                 float* __restrict__ outn,
                                                 int nrows) {
    int row  = blockIdx.x * 4 + (threadIdx.x >> 6);
    int lane = threadIdx.x & 63;
    if (row >= nrows) return;
    const float4* p = (const float4*)(in + (size_t)row * DIM) + lane * 2;
    float4 a = p[0], b = p[1];
    float s = a.x*a.x + a.y*a.y + a.z*a.z + a.w*a.w
            + b.x*b.x + b.y*b.y + b.z*b.z + b.w*b.w;
    uint4 v;
    v.x = f2bf(a.x) | (f2bf(a.y) << 16);
    v.y = f2bf(a.z) | (f2bf(a.w) << 16);
    v.z = f2bf(b.x) | (f2bf(b.y) << 16);
    v.w = f2bf(b.z) | (f2bf(b.w) << 16);
    *((uint4*)(outb + (size_t)row * DIM) + lane) = v;
#pragma unroll
    for (int off = 32; off > 0; off >>= 1) s += __shfl_xor(s, off, 64);
    if (lane == 0) outn[row] = s;
}

// plain norms (fallback path)
__global__ __launch_bounds__(256) void norms_k(const float* __restrict__ X,
                                               float* __restrict__ out,
                                               int nrows) {
    int row  = blockIdx.x * 4 + (threadIdx.x >> 6);
    int lane = threadIdx.x & 63;
    if (row >= nrows) return;
    const float4* xp = (const float4*)(X + (size_t)row * DIM);
    float4 a = xp[lane];
    float4 b = xp[lane + 64];
    float s = a.x*a.x + a.y*a.y + a.z*a.z + a.w*a.w
            + b.x*b.x + b.y*b.y + b.z*b.z + b.w*b.w;
#pragma unroll
    for (int off = 32; off > 0; off >>= 1) s += __shfl_down(s, off, 64);
    if (lane == 0) out[row] = s;
}

// ---------------------------------------------------------------------------
// top-5 insertion (sorted ascending), uint64 keys
// ---------------------------------------------------------------------------
__device__ inline void ins5(unsigned long long key, unsigned long long* top) {
    if (key < top[4]) {
        unsigned long long k0 = top[0], k1 = top[1], k2 = top[2], k3 = top[3];
        top[0] = key < k0 ? key : k0;
        top[1] = key < k0 ? k0 : (key < k1 ? key : k1);
        top[2] = key < k1 ? k1 : (key < k2 ? key : k2);
        top[3] = key < k2 ? k2 : (key < k3 ? key : k3);
        top[4] = key < k3 ? k3 : key;
    }
}

// order-preserving float -> uint map (handles negatives)
__device__ inline unsigned fmono(float v) {
    unsigned u = __float_as_uint(v);
    return (u & 0x80000000u) ? ~u : (u | 0x80000000u);
}

// inverse: float threshold from the 5th-best key's high word
__device__ inline float thr_of(unsigned long long t4) {
    if (t4 == ~0ull) return __builtin_inff();
    unsigned u = (unsigned)(t4 >> 32);
    u = (u & 0x80000000u) ? (u ^ 0x80000000u) : ~u;
    return __uint_as_float(u);
}

// ---------------------------------------------------------------------------
// Kernel 2: bf16 MFMA distance GEMM + per-(row,seg) approx top-5.
// Block 256 thr (4 waves, 2x2 of 64x64). Tile 128x128, BK=32, double-buffered
// LDS with one-step global_load_lds prefetch. Epilogue: 4 FULLY-UNROLLED
// passes of 32 cols through an 18 KB Ds buffer (total LDS 50 KB -> 3
// blocks/CU), with a float min-tree prefilter before the u64 ins5 machinery.
// NOTE: the pass loop MUST be fully unrolled — a runtime pass index makes
// acc[mt][nt] dynamically indexed and the compiler demotes acc to scratch
// (round-5 regression: 13.8 GB HBM writes, 4.5x slowdown).
// v = x2[col] - 2*cross (t2 is row-constant -> irrelevant for ordering).
// ---------------------------------------------------------------------------
__global__ __launch_bounds__(256, 3) void knn_mfma_k(
    const unsigned short* __restrict__ Xtrb,  // bf16 bits [N_TRAIN][DIM]
    const unsigned short* __restrict__ Xteb,  // bf16 bits [N_TEST][DIM]
    const float* __restrict__ x2,
    unsigned long long* __restrict__ cand)    // [N_TEST][NCAND]
{
    __shared__ __align__(16) unsigned short As[2][GTM * GBK];  // 2 x 8 KB
    __shared__ __align__(16) unsigned short Bs[2][GTN * GBK];  // 2 x 8 KB
    __shared__ __align__(16) float Ds[GTM * 36];               // 18 KB (32+4 pad)

    const int t     = threadIdx.x;
    const int lane  = t & 63;
    const int w     = t >> 6;
    const int wr    = w >> 1, wc = w & 1;
    const int col_l = lane & 15, quad = lane >> 4;
    const int row0  = blockIdx.x * GTM;
    const int seg0  = blockIdx.y * SEG;

    const int selrow = t >> 1;   // 0..127
    const int selh   = t & 1;    // 16-col half within a 32-col pass

    unsigned long long top[K_NN];
#pragma unroll
    for (int p = 0; p < K_NN; ++p) top[p] = ~0ull;
    float thr = __builtin_inff();

    // stage step s (col-tile s>>4, k-chunk s&15) into buffer b
    auto stage = [&](int s, int b) {
        const int k0   = (s & 15) * GBK;
        const int col0 = seg0 + (s >> 4) * GTN;
        const int s0 = t, s1 = 256 + t;
        GLDS16(Xteb + (size_t)(row0 + (s0 >> 2)) * DIM + k0 + (s0 & 3) * 8,
               &As[b][(w * 64) * 8]);
        GLDS16(Xteb + (size_t)(row0 + (s1 >> 2)) * DIM + k0 + (s1 & 3) * 8,
               &As[b][(256 + w * 64) * 8]);
        GLDS16(Xtrb + (size_t)(col0 + (s0 >> 2)) * DIM + k0 + (s0 & 3) * 8,
               &Bs[b][(w * 64) * 8]);
        GLDS16(Xtrb + (size_t)(col0 + (s1 >> 2)) * DIM + k0 + (s1 & 3) * 8,
               &Bs[b][(256 + w * 64) * 8]);
    };

    stage(0, 0);
    __syncthreads();   // compiler drains vmcnt(0) before the barrier

    for (int ct = 0; ct < SEG / GTN; ++ct) {
        const int col0 = seg0 + ct * GTN;
        f32x4 acc[4][4];
#pragma unroll
        for (int mt = 0; mt < 4; ++mt)
#pragma unroll
            for (int nt = 0; nt < 4; ++nt)
                acc[mt][nt] = (f32x4){0.f, 0.f, 0.f, 0.f};

#pragma unroll 2
        for (int kk = 0; kk < DIM / GBK; ++kk) {
            const int s = ct * (DIM / GBK) + kk;
            if (s + 1 < NSTEP) stage(s + 1, (s + 1) & 1);  // prefetch next step

            const unsigned short* Ab = As[s & 1];
            const unsigned short* Bb = Bs[s & 1];
            bf16x8 af[4], bfr[4];
#pragma unroll
            for (int mt = 0; mt < 4; ++mt)
                af[mt] = *(const bf16x8*)&Ab[(wr * 64 + mt * 16 + col_l) * GBK + quad * 8];
#pragma unroll
            for (int nt = 0; nt < 4; ++nt)
                bfr[nt] = *(const bf16x8*)&Bb[(wc * 64 + nt * 16 + col_l) * GBK + quad * 8];
#pragma unroll
            for (int mt = 0; mt < 4; ++mt)
#pragma unroll
                for (int nt = 0; nt < 4; ++nt)
                    acc[mt][nt] = __builtin_amdgcn_mfma_f32_16x16x32_bf16(
                        af[mt], bfr[nt], acc[mt][nt], 0, 0, 0);

            __syncthreads();   // drains prefetch (vmcnt) + frag reads (lgkm)
        }

        // epilogue: four 32-col passes through Ds — FULLY UNROLLED (see note)
#pragma unroll
        for (int p = 0; p < 4; ++p) {
            if (wc == (p >> 1)) {
#pragma unroll
                for (int q = 0; q < 2; ++q) {
                    const int nt = (p & 1) * 2 + q;             // compile-time
                    const int lc = q * 16 + col_l;              // 0..31 in pass
                    const float xv = x2[col0 + p * 32 + lc];
#pragma unroll
                    for (int mt = 0; mt < 4; ++mt) {
                        const int rb = wr * 64 + mt * 16 + quad * 4;
                        f32x4 a = acc[mt][nt];
                        Ds[(rb + 0) * 36 + lc] = fmaf(-2.f, a.x, xv);
                        Ds[(rb + 1) * 36 + lc] = fmaf(-2.f, a.y, xv);
                        Ds[(rb + 2) * 36 + lc] = fmaf(-2.f, a.z, xv);
                        Ds[(rb + 3) * 36 + lc] = fmaf(-2.f, a.w, xv);
                    }
                }
            }
            __syncthreads();
            // selection: 2 threads per row, 16 cols each, min-tree prefilter
            const int colbase = col0 + p * 32 + selh * 16;
            const int base = selrow * 36 + selh * 16;
#pragma unroll
            for (int j = 0; j < 4; ++j) {
                f32x4 v = *(const f32x4*)&Ds[base + j * 4];
                float m = fminf(fminf(v.x, v.y), fminf(v.z, v.w));
                if (m <= thr) {
                    const int cb = colbase + j * 4;
                    ins5(((unsigned long long)fmono(v.x) << 32) | (unsigned)(cb + 0), top);
                    ins5(((unsigned long long)fmono(v.y) << 32) | (unsigned)(cb + 1), top);
                    ins5(((unsigned long long)fmono(v.z) << 32) | (unsigned)(cb + 2), top);
                    ins5(((unsigned long long)fmono(v.w) << 32) | (unsigned)(cb + 3), top);
                    thr = thr_of(top[4]);
                }
            }
            __syncthreads();   // scan done before next pass overwrites Ds
        }
    }

    // merge the two half-selectors per row -> 5 keys per (row, segment)
    unsigned long long* MB2 = (unsigned long long*)Ds;   // 128 rows x 10 u64
#pragma unroll
    for (int p = 0; p < K_NN; ++p) MB2[selrow * 10 + selh * 5 + p] = top[p];
    __syncthreads();
    if (selh == 0) {
        unsigned long long m5[K_NN];
#pragma unroll
        for (int p = 0; p < K_NN; ++p) m5[p] = ~0ull;
#pragma unroll
        for (int i = 0; i < 10; ++i) ins5(MB2[selrow * 10 + i], m5);
        unsigned long long* cr =
            cand + (size_t)(row0 + selrow) * NCAND + blockIdx.y * K_NN;
#pragma unroll
        for (int p = 0; p < K_NN; ++p) cr[p] = m5[p];
    }
}

// ---------------------------------------------------------------------------
// Kernel 3: fused approx-merge (80 -> top-24) + exact fp32 rescore + vote.
// One wave per test row. Safety: true top-5 are approx-rank <= 24 with
// overwhelming margin (noise sigma ~0.1 vs order-stat gaps ~3 per rank).
// ---------------------------------------------------------------------------
__global__ __launch_bounds__(256) void rescore_vote_k(
    const float* __restrict__ Xtr, const float* __restrict__ Xte,
    const float* __restrict__ x2,  const float* __restrict__ t2,
    const unsigned long long* __restrict__ cand,
    const int* __restrict__ y, int* __restrict__ out)
{
    int row  = blockIdx.x * 4 + (threadIdx.x >> 6);
    int lane = threadIdx.x & 63;
    const unsigned long long* cr = cand + (size_t)row * NCAND;

    unsigned long long c0 = cr[lane];
    unsigned long long c1 = (lane < NCAND - 64) ? cr[64 + lane] : ~0ull;

    // iteratively extract the NRES smallest approx keys (all lanes get cols)
    unsigned cols[NRES];
#pragma unroll 1
    for (int i = 0; i < NRES; ++i) {
        unsigned long long m = c0 < c1 ? c0 : c1;
#pragma unroll
        for (int off = 32; off > 0; off >>= 1) {
            unsigned long long o = __shfl_xor(m, off, 64);
            m = o < m ? o : m;
        }
        cols[i] = (unsigned)(m & 0xffffffffu);
        if (c0 == m) c0 = ~0ull;
        if (c1 == m) c1 = ~0ull;
    }

    // exact fp32 rescore of the NRES candidates
    const float4* te = (const float4*)(Xte + (size_t)row * DIM);
    float4 e0 = te[lane * 2], e1 = te[lane * 2 + 1];
    float t2r = t2[row];
    float d2s[NRES];
#pragma unroll 4
    for (int i = 0; i < NRES; ++i) {
        const float4* tr = (const float4*)(Xtr + (size_t)cols[i] * DIM);
        float4 p = tr[lane * 2], q = tr[lane * 2 + 1];
        float s = e0.x * p.x;
        s = fmaf(e0.y, p.y, s); s = fmaf(e0.z, p.z, s); s = fmaf(e0.w, p.w, s);
        s = fmaf(e1.x, q.x, s); s = fmaf(e1.y, q.y, s);
        s = fmaf(e1.z, q.z, s); s = fmaf(e1.w, q.w, s);
#pragma unroll
        for (int off = 32; off > 0; off >>= 1) s += __shfl_xor(s, off, 64);
        d2s[i] = fmaxf(t2r + x2[cols[i]] - 2.0f * s, 0.0f);
    }

    // exact top-5 (all lanes redundantly) + mode vote on lane 0
    unsigned long long top[K_NN];
#pragma unroll
    for (int p = 0; p < K_NN; ++p) top[p] = ~0ull;
#pragma unroll
    for (int i = 0; i < NRES; ++i)
        ins5(((unsigned long long)__float_as_uint(d2s[i]) << 32) | cols[i], top);

    if (lane == 0) {
        int labs[K_NN];
#pragma unroll
        for (int p = 0; p < K_NN; ++p) labs[p] = y[(unsigned)(top[p] & 0xffffffffu)];
        int bestLab = 0x7fffffff, bestCnt = 0;
#pragma unroll
        for (int p = 0; p < K_NN; ++p) {
            int cnt = 0;
#pragma unroll
            for (int q = 0; q < K_NN; ++q) cnt += (labs[q] == labs[p]) ? 1 : 0;
            if (cnt > bestCnt || (cnt == bestCnt && labs[p] < bestLab)) {
                bestCnt = cnt; bestLab = labs[p];
            }
        }
        out[row] = bestLab;
    }
}

// ===========================================================================
// Fallback fp32 path (round-1, verified) in case ws_size is too small.
// ===========================================================================
#define FTM 64
#define FTN 128
#define FBK 16
#define FSEG (N_TRAIN / 8)

__global__ __launch_bounds__(256) void knn_tile_k(
    const float* __restrict__ Xtr, const float* __restrict__ Xte,
    const float* __restrict__ x2,  const float* __restrict__ t2,
    unsigned long long* __restrict__ cand)
{
    __shared__ float As[FBK][FTM];
    __shared__ float Bs[FBK][FTN];
    __shared__ unsigned long long MB[FTM][16 * K_NN];

    const int t   = threadIdx.x;
    const int ty  = t >> 4;
    const int tx  = t & 15;
    const int row0 = blockIdx.x * FTM;
    const int seg0 = blockIdx.y * FSEG;

    float t2r[4];
#pragma unroll
    for (int j = 0; j < 4; ++j) t2r[j] = t2[row0 + ty * 4 + j];

    unsigned long long top[4][K_NN];
#pragma unroll
    for (int j = 0; j < 4; ++j)
#pragma unroll
        for (int p = 0; p < K_NN; ++p) top[j][p] = ~0ull;

    const int srow = t >> 2;
    const int skq  = (t & 3) * 4;

    for (int ct = 0; ct < FSEG / FTN; ++ct) {
        const int col0 = seg0 + ct * FTN;
        float acc[4][8] = {};

        for (int k0 = 0; k0 < DIM; k0 += FBK) {
            float4 av  = *(const float4*)(Xte + (size_t)(row0 + srow) * DIM + k0 + skq);
            float4 bv0 = *(const float4*)(Xtr + (size_t)(col0 + srow) * DIM + k0 + skq);
            float4 bv1 = *(const float4*)(Xtr + (size_t)(col0 + 64 + srow) * DIM + k0 + skq);
            __syncthreads();
            As[skq + 0][srow] = av.x;  As[skq + 1][srow] = av.y;
            As[skq + 2][srow] = av.z;  As[skq + 3][srow] = av.w;
            Bs[skq + 0][srow] = bv0.x; Bs[skq + 1][srow] = bv0.y;
            Bs[skq + 2][srow] = bv0.z; Bs[skq + 3][srow] = bv0.w;
            Bs[skq + 0][srow + 64] = bv1.x; Bs[skq + 1][srow + 64] = bv1.y;
            Bs[skq + 2][srow + 64] = bv1.z; Bs[skq + 3][srow + 64] = bv1.w;
            __syncthreads();

#pragma unroll
            for (int k = 0; k < FBK; ++k) {
                float4 a  = *(const float4*)&As[k][ty * 4];
                float4 b0 = *(const float4*)&Bs[k][tx * 8];
                float4 b1 = *(const float4*)&Bs[k][tx * 8 + 4];
                float a4[4] = {a.x, a.y, a.z, a.w};
                float b8[8] = {b0.x, b0.y, b0.z, b0.w, b1.x, b1.y, b1.z, b1.w};
#pragma unroll
                for (int j = 0; j < 4; ++j)
#pragma unroll
                    for (int l = 0; l < 8; ++l)
                        acc[j][l] = fmaf(a4[j], b8[l], acc[j][l]);
            }
        }

#pragma unroll
        for (int j = 0; j < 4; ++j) {
#pragma unroll
            for (int l = 0; l < 8; ++l) {
                int col = col0 + tx * 8 + l;
                float d2 = fmaxf(t2r[j] + x2[col] - 2.0f * acc[j][l], 0.0f);
                unsigned long long key =
                    ((unsigned long long)__float_as_uint(d2) << 32) | (unsigned)col;
                ins5(key, top[j]);
            }
        }
    }

#pragma unroll
    for (int j = 0; j < 4; ++j)
#pragma unroll
        for (int p = 0; p < K_NN; ++p)
            MB[ty * 4 + j][tx * K_NN + p] = top[j][p];
    __syncthreads();

    if (t < FTM) {
        unsigned long long last = 0;
        for (int p = 0; p < K_NN; ++p) {
            unsigned long long best = ~0ull;
            for (int q = 0; q < 16 * K_NN; ++q) {
                unsigned long long v = MB[t][q];
                if (v > last && v < best) best = v;
            }
            cand[(size_t)(row0 + t) * 40 + blockIdx.y * K_NN + p] = best;
            last = best;
        }
    }
}

__global__ __launch_bounds__(256) void knn_final_k(
    const unsigned long long* __restrict__ cand,
    const int* __restrict__ y, int* __restrict__ out)
{
    int r = blockIdx.x * 256 + threadIdx.x;
    if (r >= N_TEST) return;
    const unsigned long long* c = cand + (size_t)r * 40;

    unsigned long long top[K_NN];
#pragma unroll
    for (int p = 0; p < K_NN; ++p) top[p] = ~0ull;
#pragma unroll
    for (int i = 0; i < 40; ++i) ins5(c[i], top);

    int labs[K_NN];
#pragma unroll
    for (int p = 0; p < K_NN; ++p) labs[p] = y[(unsigned)(top[p] & 0xffffffffu)];

    int bestLab = 0x7fffffff, bestCnt = 0;
#pragma unroll
    for (int p = 0; p < K_NN; ++p) {
        int cnt = 0;
#pragma unroll
        for (int q = 0; q < K_NN; ++q) cnt += (labs[q] == labs[p]) ? 1 : 0;
        if (cnt > bestCnt || (cnt == bestCnt && labs[p] < bestLab)) {
            bestCnt = cnt; bestLab = labs[p];
        }
    }
    out[r] = bestLab;
}

// ---------------------------------------------------------------------------
// Workspace layout (MFMA path), bytes:
//   [0,        262144)   x2     : 65536 f32
//   [262144,   278528)   t2     : 4096 f32
//   [278528,  2899968)   cand   : 4096 * 80 u64
//   [3145728, 7340032)   Xte_bf : 4096*512 bf16
//   [7340032, 74448896)  Xtr_bf : 65536*512 bf16
// ---------------------------------------------------------------------------
extern "C" void kernel_launch(void* const* d_in, const int* in_sizes, int n_in,
                              void* d_out, int out_size, void* d_ws, size_t ws_size,
                              hipStream_t stream) {
    const float* Xtr = (const float*)d_in[0];
    const float* Xte = (const float*)d_in[1];
    const int*   y   = (const int*)d_in[2];
    int* out = (int*)d_out;

    char* ws = (char*)d_ws;
    float* x2 = (float*)ws;
    float* t2 = (float*)(ws + 262144);
    unsigned long long* cand = (unsigned long long*)(ws + 278528);

    const size_t NEED = 74448896;

    if (ws_size >= NEED) {
        unsigned short* Xteb = (unsigned short*)(ws + 3145728);
        unsigned short* Xtrb = (unsigned short*)(ws + 7340032);

        cvtnorm_k<<<N_TRAIN / 4, 256, 0, stream>>>(Xtr, Xtrb, x2, N_TRAIN);
        cvtnorm_k<<<N_TEST / 4, 256, 0, stream>>>(Xte, Xteb, t2, N_TEST);

        knn_mfma_k<<<dim3(N_TEST / GTM, NSEG), 256, 0, stream>>>(Xtrb, Xteb, x2, cand);
        rescore_vote_k<<<N_TEST / 4, 256, 0, stream>>>(Xtr, Xte, x2, t2, cand, y, out);
    } else {
        // fp32 fallback (round-1 verified path); cand here is [N_TEST][40]
        norms_k<<<N_TRAIN / 4, 256, 0, stream>>>(Xtr, x2, N_TRAIN);
        norms_k<<<N_TEST / 4, 256, 0, stream>>>(Xte, t2, N_TEST);
        knn_tile_k<<<dim3(N_TEST / FTM, 8), 256, 0, stream>>>(Xtr, Xte, x2, t2, cand);
        knn_final_k<<<N_TEST / 256, 256, 0, stream>>>(cand, y, out);
    }
}

// Round 7
// 716.479 us; speedup vs baseline: 3.8254x; 1.1208x over previous
//
#include <hip/hip_runtime.h>
#include <cstdint>

// Problem constants (fixed by the reference)
#define N_TRAIN 65536
#define N_TEST  4096
#define DIM     512
#define K_NN    5
#define NSEG    32
#define SEG     (N_TRAIN / NSEG)   // 2048 train cols per segment

// MFMA path tile config. D = Xtr_tile (M=128 train cols) x Xte_tile^T
// (N=128 test rows): A-operand = TRAIN, B-operand = TEST, so each lane's
// C/D fragment (col=lane&15, row=quad*4+reg) holds 4 train cols of ONE
// test row per acc tile -> per-register top-5 selection, no LDS transpose.
#define GTM 128      // test rows per block (N dim)
#define GTN 128      // train cols per tile (M dim)
#define GBK 32       // K per step (one 16x16x32 MFMA)
#define NCAND (NSEG * K_NN)                 // 160 u32 candidates per test row
#define NRES  24                            // exactly-rescored candidates
#define NSTEP ((SEG / GTN) * (DIM / GBK))   // 16 col-tiles * 16 k-steps = 256
#define KMASK 0xFFFFF800u                   // 21-bit trunc dist | 11-bit col

typedef __bf16 bf16x8 __attribute__((ext_vector_type(8)));
typedef float  f32x4  __attribute__((ext_vector_type(4)));

#define GLDS16(g, l)                                                          \
    __builtin_amdgcn_global_load_lds(                                         \
        (__attribute__((address_space(1))) void*)(g),                         \
        (__attribute__((address_space(3))) void*)(l), 16, 0, 0)

// ---------------------------------------------------------------------------
// fp32 -> bf16 (RNE) helper
// ---------------------------------------------------------------------------
__device__ inline unsigned f2bf(float x) {
    unsigned u = __float_as_uint(x);
    return (u + 0x7FFFu + ((u >> 16) & 1u)) >> 16;
}

// ---------------------------------------------------------------------------
// Kernel 1: fused bf16 convert + squared L2 row norms. One wave per row.
// ---------------------------------------------------------------------------
__global__ __launch_bounds__(256) void cvtnorm_k(const float* __restrict__ in,
                                                 unsigned short* __restrict__ outb,
                                                 float* __restrict__ outn,
                                                 int nrows) {
    int row  = blockIdx.x * 4 + (threadIdx.x >> 6);
    int lane = threadIdx.x & 63;
    if (row >= nrows) return;
    const float4* p = (const float4*)(in + (size_t)row * DIM) + lane * 2;
    float4 a = p[0], b = p[1];
    float s = a.x*a.x + a.y*a.y + a.z*a.z + a.w*a.w
            + b.x*b.x + b.y*b.y + b.z*b.z + b.w*b.w;
    uint4 v;
    v.x = f2bf(a.x) | (f2bf(a.y) << 16);
    v.y = f2bf(a.z) | (f2bf(a.w) << 16);
    v.z = f2bf(b.x) | (f2bf(b.y) << 16);
    v.w = f2bf(b.z) | (f2bf(b.w) << 16);
    *((uint4*)(outb + (size_t)row * DIM) + lane) = v;
#pragma unroll
    for (int off = 32; off > 0; off >>= 1) s += __shfl_xor(s, off, 64);
    if (lane == 0) outn[row] = s;
}

// plain norms (fallback path)
__global__ __launch_bounds__(256) void norms_k(const float* __restrict__ X,
                                               float* __restrict__ out,
                                               int nrows) {
    int row  = blockIdx.x * 4 + (threadIdx.x >> 6);
    int lane = threadIdx.x & 63;
    if (row >= nrows) return;
    const float4* xp = (const float4*)(X + (size_t)row * DIM);
    float4 a = xp[lane];
    float4 b = xp[lane + 64];
    float s = a.x*a.x + a.y*a.y + a.z*a.z + a.w*a.w
            + b.x*b.x + b.y*b.y + b.z*b.z + b.w*b.w;
#pragma unroll
    for (int off = 32; off > 0; off >>= 1) s += __shfl_down(s, off, 64);
    if (lane == 0) out[row] = s;
}

// ---------------------------------------------------------------------------
// top-5 insertion (sorted ascending)
// ---------------------------------------------------------------------------
__device__ inline void ins5(unsigned long long key, unsigned long long* top) {
    if (key < top[4]) {
        unsigned long long k0 = top[0], k1 = top[1], k2 = top[2], k3 = top[3];
        top[0] = key < k0 ? key : k0;
        top[1] = key < k0 ? k0 : (key < k1 ? key : k1);
        top[2] = key < k1 ? k1 : (key < k2 ? key : k2);
        top[3] = key < k2 ? k2 : (key < k3 ? key : k3);
        top[4] = key < k3 ? k3 : key;
    }
}

__device__ inline void ins5u(unsigned key, unsigned* top) {
    if (key < top[4]) {
        unsigned k0 = top[0], k1 = top[1], k2 = top[2], k3 = top[3];
        top[0] = key < k0 ? key : k0;
        top[1] = key < k0 ? k0 : (key < k1 ? key : k1);
        top[2] = key < k1 ? k1 : (key < k2 ? key : k2);
        top[3] = key < k2 ? k2 : (key < k3 ? key : k3);
        top[4] = key < k3 ? k3 : key;
    }
}

// order-preserving float -> uint map (handles negatives)
__device__ inline unsigned fmono(float v) {
    unsigned u = __float_as_uint(v);
    return (u & 0x80000000u) ? ~u : (u | 0x80000000u);
}

// ---------------------------------------------------------------------------
// Kernel 2: bf16 MFMA distance GEMM, operand-swapped, register epilogue.
// Block 256 thr (4 waves, wr x wc = train-half x test-half, 64x64 each).
// Tile 128 train x 128 test, BK=32, double-buffered LDS + 1-step prefetch.
// Per-thread tops live in LDS (stride 21 u32 -> conflict-free), thresholds
// cached in VGPRs; fast path per (tile, test-row) = 16 fmaf + min-tree + 1 cmp.
// NOTE: all acc[] indices must be compile-time (round-5 scratch regression).
// v = x2[col] - 2*cross (t2 row-constant -> irrelevant for ordering).
// ---------------------------------------------------------------------------
__global__ __launch_bounds__(256, 3) void knn_mfma_k(
    const unsigned short* __restrict__ Xtrb,  // bf16 bits [N_TRAIN][DIM]
    const unsigned short* __restrict__ Xteb,  // bf16 bits [N_TEST][DIM]
    const float* __restrict__ x2,
    unsigned* __restrict__ cand)              // [N_TEST][NCAND] u32 keys
{
    __shared__ __align__(16) unsigned short As[2][GTM * GBK];  // test,  2x8 KB
    __shared__ __align__(16) unsigned short Bs[2][GTN * GBK];  // train, 2x8 KB
    __shared__ unsigned MB[256 * 21];   // per-thread tops [tid][nt*5+p], pad->21

    const int t     = threadIdx.x;
    const int lane  = t & 63;
    const int w     = t >> 6;
    const int wr    = w >> 1, wc = w & 1;   // wr: train half (M), wc: test half (N)
    const int col_l = lane & 15, quad = lane >> 4;
    const int row0  = blockIdx.x * GTM;
    const int seg0  = blockIdx.y * SEG;

    unsigned* myMB = &MB[t * 21];
#pragma unroll
    for (int i = 0; i < 20; ++i) myMB[i] = 0xFFFFFFFFu;
    unsigned thr[4];
#pragma unroll
    for (int nt = 0; nt < 4; ++nt) thr[nt] = 0xFFFFFFFFu;

    // stage step s (col-tile s>>4, k-chunk s&15) into buffer b
    auto stage = [&](int s, int b) {
        const int k0   = (s & 15) * GBK;
        const int col0 = seg0 + (s >> 4) * GTN;
        const int s0 = t, s1 = 256 + t;
        GLDS16(Xteb + (size_t)(row0 + (s0 >> 2)) * DIM + k0 + (s0 & 3) * 8,
               &As[b][(w * 64) * 8]);
        GLDS16(Xteb + (size_t)(row0 + (s1 >> 2)) * DIM + k0 + (s1 & 3) * 8,
               &As[b][(256 + w * 64) * 8]);
        GLDS16(Xtrb + (size_t)(col0 + (s0 >> 2)) * DIM + k0 + (s0 & 3) * 8,
               &Bs[b][(w * 64) * 8]);
        GLDS16(Xtrb + (size_t)(col0 + (s1 >> 2)) * DIM + k0 + (s1 & 3) * 8,
               &Bs[b][(256 + w * 64) * 8]);
    };

    stage(0, 0);
    __syncthreads();   // compiler drains vmcnt(0) before the barrier

    for (int ct = 0; ct < SEG / GTN; ++ct) {
        const int col0 = seg0 + ct * GTN;
        f32x4 acc[4][4];   // [mt: train tile][nt: test tile]
#pragma unroll
        for (int mt = 0; mt < 4; ++mt)
#pragma unroll
            for (int nt = 0; nt < 4; ++nt)
                acc[mt][nt] = (f32x4){0.f, 0.f, 0.f, 0.f};

        // x2 for this thread's 16 train cols (4 per mt, contiguous at quad*4)
        f32x4 x2r[4];
#pragma unroll
        for (int mt = 0; mt < 4; ++mt)
            x2r[mt] = *(const f32x4*)&x2[col0 + wr * 64 + mt * 16 + quad * 4];

#pragma unroll 2
        for (int kk = 0; kk < DIM / GBK; ++kk) {
            const int s = ct * (DIM / GBK) + kk;
            if (s + 1 < NSTEP) stage(s + 1, (s + 1) & 1);  // prefetch next step

            const unsigned short* Ab = As[s & 1];   // test
            const unsigned short* Bb = Bs[s & 1];   // train
            bf16x8 trf[4], tef[4];
#pragma unroll
            for (int mt = 0; mt < 4; ++mt)   // A-operand = train rows (M)
                trf[mt] = *(const bf16x8*)&Bb[(wr * 64 + mt * 16 + col_l) * GBK + quad * 8];
#pragma unroll
            for (int nt = 0; nt < 4; ++nt)   // B-operand = test rows (N)
                tef[nt] = *(const bf16x8*)&Ab[(wc * 64 + nt * 16 + col_l) * GBK + quad * 8];
#pragma unroll
            for (int mt = 0; mt < 4; ++mt)
#pragma unroll
                for (int nt = 0; nt < 4; ++nt)
                    acc[mt][nt] = __builtin_amdgcn_mfma_f32_16x16x32_bf16(
                        trf[mt], tef[nt], acc[mt][nt], 0, 0, 0);

            __syncthreads();   // drains prefetch (vmcnt) + frag reads (lgkm)
        }

        // register epilogue: per nt (one test row), 16 train cols in acc
        const int cb = ct * GTN + wr * 64 + quad * 4;   // segment-local col base
#pragma unroll
        for (int nt = 0; nt < 4; ++nt) {
            float dv[16];
            float dmin = __builtin_inff();
#pragma unroll
            for (int mt = 0; mt < 4; ++mt) {
                f32x4 a = acc[mt][nt];
                dv[mt * 4 + 0] = fmaf(-2.f, a.x, x2r[mt].x);
                dv[mt * 4 + 1] = fmaf(-2.f, a.y, x2r[mt].y);
                dv[mt * 4 + 2] = fmaf(-2.f, a.z, x2r[mt].z);
                dv[mt * 4 + 3] = fmaf(-2.f, a.w, x2r[mt].w);
                float g = fminf(fminf(dv[mt*4+0], dv[mt*4+1]),
                                fminf(dv[mt*4+2], dv[mt*4+3]));
                dmin = fminf(dmin, g);
            }
            if ((fmono(dmin) & KMASK) <= thr[nt]) {   // rare path
                unsigned tp[K_NN];
#pragma unroll
                for (int p = 0; p < K_NN; ++p) tp[p] = myMB[nt * K_NN + p];
#pragma unroll
                for (int mt = 0; mt < 4; ++mt) {
                    float g = fminf(fminf(dv[mt*4+0], dv[mt*4+1]),
                                    fminf(dv[mt*4+2], dv[mt*4+3]));
                    if ((fmono(g) & KMASK) <= tp[4]) {
#pragma unroll
                        for (int i = 0; i < 4; ++i) {
                            unsigned key = (fmono(dv[mt * 4 + i]) & KMASK)
                                         | (unsigned)(cb + mt * 16 + i);
                            ins5u(key, tp);
                        }
                    }
                }
#pragma unroll
                for (int p = 0; p < K_NN; ++p) myMB[nt * K_NN + p] = tp[p];
                thr[nt] = tp[4];
            }
        }
    }

    __syncthreads();
    // final merge: one thread per test row, 8 sub-lists (wr x quad) of 5
    if (t < GTM) {
        const int r   = t;
        const int mwc = r >> 6, mnt = (r >> 4) & 3, mcl = r & 15;
        unsigned tp[K_NN];
#pragma unroll
        for (int p = 0; p < K_NN; ++p) tp[p] = 0xFFFFFFFFu;
#pragma unroll
        for (int w2 = 0; w2 < 2; ++w2)
#pragma unroll
            for (int q = 0; q < 4; ++q) {
                const int tid = (w2 * 2 + mwc) * 64 + q * 16 + mcl;
                const unsigned* src = &MB[tid * 21 + mnt * K_NN];
#pragma unroll
                for (int p = 0; p < K_NN; ++p) ins5u(src[p], tp);
            }
        unsigned* cr = cand + (size_t)(row0 + r) * NCAND + blockIdx.y * K_NN;
#pragma unroll
        for (int p = 0; p < K_NN; ++p) cr[p] = tp[p];
    }
}

// ---------------------------------------------------------------------------
// Kernel 3: fused approx-merge (160 -> top-24) + exact fp32 rescore + vote.
// One wave per test row. cand entries are u32: trunc-dist(21) | col-local(11);
// global col = (entry_index/5)*SEG + col-local.
// ---------------------------------------------------------------------------
__global__ __launch_bounds__(256) void rescore_vote_k(
    const float* __restrict__ Xtr, const float* __restrict__ Xte,
    const float* __restrict__ x2,  const float* __restrict__ t2,
    const unsigned* __restrict__ cand,
    const int* __restrict__ y, int* __restrict__ out)
{
    int row  = blockIdx.x * 4 + (threadIdx.x >> 6);
    int lane = threadIdx.x & 63;
    const unsigned* cr = cand + (size_t)row * NCAND;

    auto expand = [](unsigned k, int e) -> unsigned long long {
        unsigned gcol = (unsigned)(e / K_NN) * SEG + (k & 0x7FFu);
        return ((unsigned long long)k << 32) | gcol;
    };
    unsigned long long c0 = expand(cr[lane], lane);
    unsigned long long c1 = expand(cr[64 + lane], 64 + lane);
    unsigned long long c2 = (lane < NCAND - 128)
                          ? expand(cr[128 + lane], 128 + lane) : ~0ull;

    // iteratively extract the NRES smallest approx keys (all lanes get cols)
    unsigned cols[NRES];
#pragma unroll 1
    for (int i = 0; i < NRES; ++i) {
        unsigned long long m = c0 < c1 ? c0 : c1;
        m = c2 < m ? c2 : m;
#pragma unroll
        for (int off = 32; off > 0; off >>= 1) {
            unsigned long long o = __shfl_xor(m, off, 64);
            m = o < m ? o : m;
        }
        cols[i] = (unsigned)(m & 0xffffffffu);
        if (c0 == m) c0 = ~0ull;
        if (c1 == m) c1 = ~0ull;
        if (c2 == m) c2 = ~0ull;
    }

    // exact fp32 rescore of the NRES candidates
    const float4* te = (const float4*)(Xte + (size_t)row * DIM);
    float4 e0 = te[lane * 2], e1 = te[lane * 2 + 1];
    float t2r = t2[row];
    float d2s[NRES];
#pragma unroll 4
    for (int i = 0; i < NRES; ++i) {
        const float4* tr = (const float4*)(Xtr + (size_t)cols[i] * DIM);
        float4 p = tr[lane * 2], q = tr[lane * 2 + 1];
        float s = e0.x * p.x;
        s = fmaf(e0.y, p.y, s); s = fmaf(e0.z, p.z, s); s = fmaf(e0.w, p.w, s);
        s = fmaf(e1.x, q.x, s); s = fmaf(e1.y, q.y, s);
        s = fmaf(e1.z, q.z, s); s = fmaf(e1.w, q.w, s);
#pragma unroll
        for (int off = 32; off > 0; off >>= 1) s += __shfl_xor(s, off, 64);
        d2s[i] = fmaxf(t2r + x2[cols[i]] - 2.0f * s, 0.0f);
    }

    // exact top-5 (all lanes redundantly) + mode vote on lane 0
    unsigned long long top[K_NN];
#pragma unroll
    for (int p = 0; p < K_NN; ++p) top[p] = ~0ull;
#pragma unroll
    for (int i = 0; i < NRES; ++i)
        ins5(((unsigned long long)__float_as_uint(d2s[i]) << 32) | cols[i], top);

    if (lane == 0) {
        int labs[K_NN];
#pragma unroll
        for (int p = 0; p < K_NN; ++p) labs[p] = y[(unsigned)(top[p] & 0xffffffffu)];
        int bestLab = 0x7fffffff, bestCnt = 0;
#pragma unroll
        for (int p = 0; p < K_NN; ++p) {
            int cnt = 0;
#pragma unroll
            for (int q = 0; q < K_NN; ++q) cnt += (labs[q] == labs[p]) ? 1 : 0;
            if (cnt > bestCnt || (cnt == bestCnt && labs[p] < bestLab)) {
                bestCnt = cnt; bestLab = labs[p];
            }
        }
        out[row] = bestLab;
    }
}

// ===========================================================================
// Fallback fp32 path (round-1, verified) in case ws_size is too small.
// ===========================================================================
#define FTM 64
#define FTN 128
#define FBK 16
#define FSEG (N_TRAIN / 8)

__global__ __launch_bounds__(256) void knn_tile_k(
    const float* __restrict__ Xtr, const float* __restrict__ Xte,
    const float* __restrict__ x2,  const float* __restrict__ t2,
    unsigned long long* __restrict__ cand)
{
    __shared__ float As[FBK][FTM];
    __shared__ float Bs[FBK][FTN];
    __shared__ unsigned long long MB[FTM][16 * K_NN];

    const int t   = threadIdx.x;
    const int ty  = t >> 4;
    const int tx  = t & 15;
    const int row0 = blockIdx.x * FTM;
    const int seg0 = blockIdx.y * FSEG;

    float t2r[4];
#pragma unroll
    for (int j = 0; j < 4; ++j) t2r[j] = t2[row0 + ty * 4 + j];

    unsigned long long top[4][K_NN];
#pragma unroll
    for (int j = 0; j < 4; ++j)
#pragma unroll
        for (int p = 0; p < K_NN; ++p) top[j][p] = ~0ull;

    const int srow = t >> 2;
    const int skq  = (t & 3) * 4;

    for (int ct = 0; ct < FSEG / FTN; ++ct) {
        const int col0 = seg0 + ct * FTN;
        float acc[4][8] = {};

        for (int k0 = 0; k0 < DIM; k0 += FBK) {
            float4 av  = *(const float4*)(Xte + (size_t)(row0 + srow) * DIM + k0 + skq);
            float4 bv0 = *(const float4*)(Xtr + (size_t)(col0 + srow) * DIM + k0 + skq);
            float4 bv1 = *(const float4*)(Xtr + (size_t)(col0 + 64 + srow) * DIM + k0 + skq);
            __syncthreads();
            As[skq + 0][srow] = av.x;  As[skq + 1][srow] = av.y;
            As[skq + 2][srow] = av.z;  As[skq + 3][srow] = av.w;
            Bs[skq + 0][srow] = bv0.x; Bs[skq + 1][srow] = bv0.y;
            Bs[skq + 2][srow] = bv0.z; Bs[skq + 3][srow] = bv0.w;
            Bs[skq + 0][srow + 64] = bv1.x; Bs[skq + 1][srow + 64] = bv1.y;
            Bs[skq + 2][srow + 64] = bv1.z; Bs[skq + 3][srow + 64] = bv1.w;
            __syncthreads();

#pragma unroll
            for (int k = 0; k < FBK; ++k) {
                float4 a  = *(const float4*)&As[k][ty * 4];
                float4 b0 = *(const float4*)&Bs[k][tx * 8];
                float4 b1 = *(const float4*)&Bs[k][tx * 8 + 4];
                float a4[4] = {a.x, a.y, a.z, a.w};
                float b8[8] = {b0.x, b0.y, b0.z, b0.w, b1.x, b1.y, b1.z, b1.w};
#pragma unroll
                for (int j = 0; j < 4; ++j)
#pragma unroll
                    for (int l = 0; l < 8; ++l)
                        acc[j][l] = fmaf(a4[j], b8[l], acc[j][l]);
            }
        }

#pragma unroll
        for (int j = 0; j < 4; ++j) {
#pragma unroll
            for (int l = 0; l < 8; ++l) {
                int col = col0 + tx * 8 + l;
                float d2 = fmaxf(t2r[j] + x2[col] - 2.0f * acc[j][l], 0.0f);
                unsigned long long key =
                    ((unsigned long long)__float_as_uint(d2) << 32) | (unsigned)col;
                ins5(key, top[j]);
            }
        }
    }

#pragma unroll
    for (int j = 0; j < 4; ++j)
#pragma unroll
        for (int p = 0; p < K_NN; ++p)
            MB[ty * 4 + j][tx * K_NN + p] = top[j][p];
    __syncthreads();

    if (t < FTM) {
        unsigned long long last = 0;
        for (int p = 0; p < K_NN; ++p) {
            unsigned long long best = ~0ull;
            for (int q = 0; q < 16 * K_NN; ++q) {
                unsigned long long v = MB[t][q];
                if (v > last && v < best) best = v;
            }
            cand[(size_t)(row0 + t) * 40 + blockIdx.y * K_NN + p] = best;
            last = best;
        }
    }
}

__global__ __launch_bounds__(256) void knn_final_k(
    const unsigned long long* __restrict__ cand,
    const int* __restrict__ y, int* __restrict__ out)
{
    int r = blockIdx.x * 256 + threadIdx.x;
    if (r >= N_TEST) return;
    const unsigned long long* c = cand + (size_t)r * 40;

    unsigned long long top[K_NN];
#pragma unroll
    for (int p = 0; p < K_NN; ++p) top[p] = ~0ull;
#pragma unroll
    for (int i = 0; i < 40; ++i) ins5(c[i], top);

    int labs[K_NN];
#pragma unroll
    for (int p = 0; p < K_NN; ++p) labs[p] = y[(unsigned)(top[p] & 0xffffffffu)];

    int bestLab = 0x7fffffff, bestCnt = 0;
#pragma unroll
    for (int p = 0; p < K_NN; ++p) {
        int cnt = 0;
#pragma unroll
        for (int q = 0; q < K_NN; ++q) cnt += (labs[q] == labs[p]) ? 1 : 0;
        if (cnt > bestCnt || (cnt == bestCnt && labs[p] < bestLab)) {
            bestCnt = cnt; bestLab = labs[p];
        }
    }
    out[r] = bestLab;
}

// ---------------------------------------------------------------------------
// Workspace layout (MFMA path), bytes (NEED unchanged from round 4/6):
//   [0,        262144)   x2     : 65536 f32
//   [262144,   278528)   t2     : 4096 f32
//   [278528,  2899968)   cand   : 4096 * 160 u32 (exactly fills old slot)
//   [3145728, 7340032)   Xte_bf : 4096*512 bf16
//   [7340032, 74448896)  Xtr_bf : 65536*512 bf16
// ---------------------------------------------------------------------------
extern "C" void kernel_launch(void* const* d_in, const int* in_sizes, int n_in,
                              void* d_out, int out_size, void* d_ws, size_t ws_size,
                              hipStream_t stream) {
    const float* Xtr = (const float*)d_in[0];
    const float* Xte = (const float*)d_in[1];
    const int*   y   = (const int*)d_in[2];
    int* out = (int*)d_out;

    char* ws = (char*)d_ws;
    float* x2 = (float*)ws;
    float* t2 = (float*)(ws + 262144);

    const size_t NEED = 74448896;

    if (ws_size >= NEED) {
        unsigned* cand = (unsigned*)(ws + 278528);
        unsigned short* Xteb = (unsigned short*)(ws + 3145728);
        unsigned short* Xtrb = (unsigned short*)(ws + 7340032);

        cvtnorm_k<<<N_TRAIN / 4, 256, 0, stream>>>(Xtr, Xtrb, x2, N_TRAIN);
        cvtnorm_k<<<N_TEST / 4, 256, 0, stream>>>(Xte, Xteb, t2, N_TEST);

        knn_mfma_k<<<dim3(N_TEST / GTM, NSEG), 256, 0, stream>>>(Xtrb, Xteb, x2, cand);
        rescore_vote_k<<<N_TEST / 4, 256, 0, stream>>>(Xtr, Xte, x2, t2, cand, y, out);
    } else {
        // fp32 fallback (round-1 verified path); cand here is [N_TEST][40] u64
        unsigned long long* cand = (unsigned long long*)(ws + 278528);
        norms_k<<<N_TRAIN / 4, 256, 0, stream>>>(Xtr, x2, N_TRAIN);
        norms_k<<<N_TEST / 4, 256, 0, stream>>>(Xte, t2, N_TEST);
        knn_tile_k<<<dim3(N_TEST / FTM, 8), 256, 0, stream>>>(Xtr, Xte, x2, t2, cand);
        knn_final_k<<<N_TEST / 256, 256, 0, stream>>>(cand, y, out);
    }
}